// Round 5
// baseline (138.935 us; speedup 1.0000x reference)
//
#include <hip/hip_runtime.h>
#include <hip/hip_cooperative_groups.h>

namespace cg = cooperative_groups;

#define D_EMB   64
#define D_HID   128
#define NUM_EL  118

// ===========================================================================
// Fused single-dispatch kernel (cooperative launch, grid = B = 1024 blocks).
// Phase 1:
//   blocks 118..1023 : zero first half of forces (float4) + int4 diff-pass
//                      of sorted batch -> starts[0..B]
//   blocks   0..117  : per-element MLP -> Etab[z]   (latency-bound; overlaps)
// grid.sync()
// Phase 2:
//   block b : zero second half of forces + sum Etab over segment b -> energy[b]
// ===========================================================================
__global__ __launch_bounds__(256, 4)
void mace_fused_kernel(const float* __restrict__ embed,
                       const float* __restrict__ W1, const float* __restrict__ b1,
                       const float* __restrict__ W2, const float* __restrict__ b2,
                       const float* __restrict__ W3, const float* __restrict__ b3,
                       const int* __restrict__ z,
                       const int* __restrict__ batch,
                       float* __restrict__ energy,
                       float4* __restrict__ forces4,
                       float* __restrict__ Etab,
                       int* __restrict__ starts,
                       int n, int B, int nf4) {
    __shared__ float h[D_EMB];
    __shared__ float x1[D_HID];
    __shared__ float wsum2[2];
    __shared__ float etab_s[NUM_EL];
    __shared__ float wsum[4];

    const int t   = threadIdx.x;
    const int bid = blockIdx.x;
    const float4 z4f = make_float4(0.f, 0.f, 0.f, 0.f);
    const int half4 = nf4 >> 1;

    if (bid >= NUM_EL) {
        // ----- bulk memory blocks -----
        const int wid     = (bid - NUM_EL) * 256 + t;
        const int wstride = (gridDim.x - NUM_EL) * 256;

        // zero first half of forces
        for (int i = wid; i < half4; i += wstride) forces4[i] = z4f;

        // diff-pass: each element read once via int4
        const int4* __restrict__ batch4 = (const int4*)batch;
        const int n4 = n >> 2;
        for (int i4 = wid; i4 < n4; i4 += wstride) {
            const int4 v = batch4[i4];
            const int base = i4 << 2;
            if (v.x != v.y) { for (int b = v.x + 1; b <= v.y; ++b) starts[b] = base + 1; }
            if (v.y != v.z) { for (int b = v.y + 1; b <= v.z; ++b) starts[b] = base + 2; }
            if (v.z != v.w) { for (int b = v.z + 1; b <= v.w; ++b) starts[b] = base + 3; }
            if (base + 4 < n) {
                const int nx = batch[base + 4];
                if (v.w != nx) { for (int b = v.w + 1; b <= nx; ++b) starts[b] = base + 4; }
            }
        }
        if (wid == 0) {
            const int first = batch[0], last = batch[n - 1];
            for (int b = 0; b <= first; ++b) starts[b] = 0;
            for (int b = last + 1; b <= B; ++b) starts[b] = n;
        }
    } else {
        // ----- MLP block: element index = bid -----
        if (t < D_EMB) h[t] = embed[bid * D_EMB + t];
        __syncthreads();

        if (t < D_HID) {
            float a0 = 0.f, a1 = 0.f, a2 = 0.f, a3 = 0.f;
            #pragma unroll
            for (int k = 0; k < D_EMB; k += 4) {
                a0 = fmaf(h[k + 0], W1[(k + 0) * D_HID + t], a0);
                a1 = fmaf(h[k + 1], W1[(k + 1) * D_HID + t], a1);
                a2 = fmaf(h[k + 2], W1[(k + 2) * D_HID + t], a2);
                a3 = fmaf(h[k + 3], W1[(k + 3) * D_HID + t], a3);
            }
            const float acc = b1[t] + ((a0 + a1) + (a2 + a3));
            x1[t] = acc / (1.0f + expf(-acc));
        }
        __syncthreads();

        float r = 0.f;
        if (t < D_HID) {
            float a0 = 0.f, a1 = 0.f, a2 = 0.f, a3 = 0.f;
            #pragma unroll
            for (int k = 0; k < D_HID; k += 4) {
                a0 = fmaf(x1[k + 0], W2[(k + 0) * D_HID + t], a0);
                a1 = fmaf(x1[k + 1], W2[(k + 1) * D_HID + t], a1);
                a2 = fmaf(x1[k + 2], W2[(k + 2) * D_HID + t], a2);
                a3 = fmaf(x1[k + 3], W2[(k + 3) * D_HID + t], a3);
            }
            const float acc2 = b2[t] + ((a0 + a1) + (a2 + a3));
            const float s2 = acc2 / (1.0f + expf(-acc2));
            r = s2 * W3[t];
        }
        #pragma unroll
        for (int off = 32; off > 0; off >>= 1)
            r += __shfl_down(r, off, 64);
        if (t < D_HID && (t & 63) == 0) wsum2[t >> 6] = r;
        __syncthreads();
        if (t == 0) Etab[bid] = wsum2[0] + wsum2[1] + b3[0];
    }

    cg::this_grid().sync();

    // ================= Phase 2: block bid <-> molecule bid =================
    // zero second half of forces (stores issued first, fire-and-forget)
    {
        const int gstride = gridDim.x * 256;
        for (int i = half4 + bid * 256 + t; i < nf4; i += gstride) forces4[i] = z4f;
    }

    if (t < NUM_EL) etab_s[t] = Etab[t];
    const int start = starts[bid];
    const int end   = starts[bid + 1];
    __syncthreads();

    float acc = 0.f;
    int a0 = (start + 3) & ~3;
    if (a0 > end) a0 = end;
    const int a1 = (end >= a0) ? (end & ~3) : a0;

    if (t < a0 - start) acc += etab_s[z[start + t]];          // head (<4)
    if (a1 >= a0 && t < end - a1) acc += etab_s[z[a1 + t]];   // tail (<4)

    const int4* __restrict__ zz4 = (const int4*)z;
    for (int i4 = (a0 >> 2) + t; i4 < (a1 >> 2); i4 += 256) {
        const int4 v = zz4[i4];
        acc += (etab_s[v.x] + etab_s[v.y]) + (etab_s[v.z] + etab_s[v.w]);
    }

    #pragma unroll
    for (int off = 32; off > 0; off >>= 1)
        acc += __shfl_down(acc, off, 64);
    if ((t & 63) == 0) wsum[t >> 6] = acc;
    __syncthreads();
    if (t == 0) energy[bid] = (wsum[0] + wsum[1]) + (wsum[2] + wsum[3]);
}

// ===========================================================================
// Fallback path (proven round-4 structure) in case cooperative launch is
// rejected: prep kernel + segsum kernel.
// ===========================================================================
__global__ __launch_bounds__(256)
void mace_prep_kernel(const float* __restrict__ embed,
                      const float* __restrict__ W1, const float* __restrict__ b1,
                      const float* __restrict__ W2, const float* __restrict__ b2,
                      const float* __restrict__ W3, const float* __restrict__ b3,
                      float* __restrict__ Etab,
                      int* __restrict__ starts,
                      const int* __restrict__ batch, int n, int B,
                      float4* __restrict__ forces4, int nf4) {
    const int t = threadIdx.x;
    const int gid = blockIdx.x * blockDim.x + t;
    const int gstride = gridDim.x * blockDim.x;

    for (int i = gid; i < nf4; i += gstride)
        forces4[i] = make_float4(0.f, 0.f, 0.f, 0.f);

    for (int i = gid; i < n - 1; i += gstride) {
        const int c0 = batch[i];
        const int c1 = batch[i + 1];
        if (c0 != c1) {
            for (int b = c0 + 1; b <= c1; ++b) starts[b] = i + 1;
        }
    }
    if (gid == 0) {
        const int first = batch[0], last = batch[n - 1];
        for (int b = 0; b <= first; ++b) starts[b] = 0;
        for (int b = last + 1; b <= B; ++b) starts[b] = n;
    }

    if (blockIdx.x < NUM_EL) {
        __shared__ float h[D_EMB];
        __shared__ float x1[D_HID];
        __shared__ float wsum[2];
        const int zz = blockIdx.x;

        if (t < D_EMB) h[t] = embed[zz * D_EMB + t];
        __syncthreads();
        if (t < D_HID) {
            float a0 = 0.f, a1 = 0.f, a2 = 0.f, a3 = 0.f;
            #pragma unroll
            for (int k = 0; k < D_EMB; k += 4) {
                a0 = fmaf(h[k + 0], W1[(k + 0) * D_HID + t], a0);
                a1 = fmaf(h[k + 1], W1[(k + 1) * D_HID + t], a1);
                a2 = fmaf(h[k + 2], W1[(k + 2) * D_HID + t], a2);
                a3 = fmaf(h[k + 3], W1[(k + 3) * D_HID + t], a3);
            }
            const float acc = b1[t] + ((a0 + a1) + (a2 + a3));
            x1[t] = acc / (1.0f + expf(-acc));
        }
        __syncthreads();
        float r = 0.f;
        if (t < D_HID) {
            float a0 = 0.f, a1 = 0.f, a2 = 0.f, a3 = 0.f;
            #pragma unroll
            for (int k = 0; k < D_HID; k += 4) {
                a0 = fmaf(x1[k + 0], W2[(k + 0) * D_HID + t], a0);
                a1 = fmaf(x1[k + 1], W2[(k + 1) * D_HID + t], a1);
                a2 = fmaf(x1[k + 2], W2[(k + 2) * D_HID + t], a2);
                a3 = fmaf(x1[k + 3], W2[(k + 3) * D_HID + t], a3);
            }
            const float acc2 = b2[t] + ((a0 + a1) + (a2 + a3));
            const float s2 = acc2 / (1.0f + expf(-acc2));
            r = s2 * W3[t];
        }
        #pragma unroll
        for (int off = 32; off > 0; off >>= 1)
            r += __shfl_down(r, off, 64);
        if (t < D_HID && (t & 63) == 0) wsum[t >> 6] = r;
        __syncthreads();
        if (t == 0) Etab[zz] = wsum[0] + wsum[1] + b3[0];
    }
}

__global__ __launch_bounds__(256)
void mace_segsum_kernel(const int* __restrict__ z,
                        const int* __restrict__ starts,
                        const float* __restrict__ EtabG,
                        float* __restrict__ energy) {
    __shared__ float etab_s[NUM_EL];
    __shared__ float wsum[4];
    const int b = blockIdx.x;
    const int t = threadIdx.x;
    const int w = t >> 6;

    if (t < NUM_EL) etab_s[t] = EtabG[t];
    const int start = starts[b];
    const int end   = starts[b + 1];
    __syncthreads();

    float acc = 0.f;
    int a0 = (start + 3) & ~3;
    if (a0 > end) a0 = end;
    const int a1 = (end >= a0) ? (end & ~3) : a0;

    if (t < a0 - start) acc += etab_s[z[start + t]];
    if (a1 >= a0 && t < end - a1) acc += etab_s[z[a1 + t]];

    const int4* __restrict__ z4 = (const int4*)z;
    for (int i4 = (a0 >> 2) + t; i4 < (a1 >> 2); i4 += 256) {
        const int4 v = z4[i4];
        acc += (etab_s[v.x] + etab_s[v.y]) + (etab_s[v.z] + etab_s[v.w]);
    }

    #pragma unroll
    for (int off = 32; off > 0; off >>= 1)
        acc += __shfl_down(acc, off, 64);
    if ((t & 63) == 0) wsum[w] = acc;
    __syncthreads();
    if (t == 0) energy[b] = (wsum[0] + wsum[1]) + (wsum[2] + wsum[3]);
}

extern "C" void kernel_launch(void* const* d_in, const int* in_sizes, int n_in,
                              void* d_out, int out_size, void* d_ws, size_t ws_size,
                              hipStream_t stream) {
    // 0 positions, 1 embed, 2 W1, 3 b1, 4 W2, 5 b2, 6 W3, 7 b3,
    // 8 atomic_numbers, 9 batch
    const float* embed = (const float*)d_in[1];
    const float* W1    = (const float*)d_in[2];
    const float* b1    = (const float*)d_in[3];
    const float* W2    = (const float*)d_in[4];
    const float* b2    = (const float*)d_in[5];
    const float* W3    = (const float*)d_in[6];
    const float* b3    = (const float*)d_in[7];
    const int*   z     = (const int*)d_in[8];
    const int*   batch = (const int*)d_in[9];
    int          n     = in_sizes[8];               // 1,000,000

    int B   = out_size - 3 * n;                     // 1024
    int nf4 = (3 * n) / 4;                          // 750,000

    float*  energy  = (float*)d_out;                 // [B]
    float4* forces4 = (float4*)((float*)d_out + B);  // [3N], 16B-aligned
    float*  Etab    = (float*)d_ws;                  // 118 floats
    int*    starts  = (int*)d_ws + 128;              // B+1 ints

    void* args[] = {
        (void*)&embed, (void*)&W1, (void*)&b1, (void*)&W2, (void*)&b2,
        (void*)&W3, (void*)&b3, (void*)&z, (void*)&batch,
        (void*)&energy, (void*)&forces4, (void*)&Etab, (void*)&starts,
        (void*)&n, (void*)&B, (void*)&nf4
    };
    hipError_t err = hipLaunchCooperativeKernel((const void*)mace_fused_kernel,
                                                dim3(B), dim3(256), args, 0, stream);
    if (err != hipSuccess) {
        (void)hipGetLastError();   // clear sticky error; fall back to 2-kernel path
        mace_prep_kernel<<<2048, 256, 0, stream>>>(embed, W1, b1, W2, b2, W3, b3,
                                                   Etab, starts, batch, n, B,
                                                   forces4, nf4);
        mace_segsum_kernel<<<B, 256, 0, stream>>>(z, starts, Etab, energy);
    }
}

// Round 6
// 15.248 us; speedup vs baseline: 9.1117x; 9.1117x over previous
//
#include <hip/hip_runtime.h>

#define D_EMB   64
#define D_HID   128
#define NUM_EL  118
#define CHUNK   1024     // atoms per block in kernel 2 (4 per thread, one int4)
#define NBINS   16       // molecules spanned by one 1024-atom chunk (avg seg ~977)

// ---------------------------------------------------------------------------
// Kernel 1: per-element energy table (118 blocks x 256 threads; 2 threads per
// hidden unit halve the serial fma chain) + zero the energy output.
// ---------------------------------------------------------------------------
__global__ __launch_bounds__(256)
void mace_etab_kernel(const float* __restrict__ embed,
                      const float* __restrict__ W1, const float* __restrict__ b1,
                      const float* __restrict__ W2, const float* __restrict__ b2,
                      const float* __restrict__ W3, const float* __restrict__ b3,
                      float* __restrict__ Etab, float* __restrict__ energy, int B) {
    __shared__ float h[D_EMB];
    __shared__ float x1[D_HID];
    __shared__ float part[D_HID];
    __shared__ float wsum[2];
    const int t  = threadIdx.x;
    const int j  = t & 127;       // hidden unit
    const int hf = t >> 7;        // which half of the k-range
    const int zz = blockIdx.x;

    // zero energy[B] (atomics in kernel 2 accumulate on top)
    for (int i = blockIdx.x * 256 + t; i < B; i += NUM_EL * 256)
        energy[i] = 0.f;

    if (t < D_EMB) h[t] = embed[zz * D_EMB + t];
    __syncthreads();

    // ---- layer 1: acc = b1 + h@W1 ; k-range split 32/32 across hf ----
    {
        const int k0 = hf * 32;
        float a0 = 0.f, a1 = 0.f, a2 = 0.f, a3 = 0.f;
        #pragma unroll
        for (int k = 0; k < 32; k += 4) {
            a0 = fmaf(h[k0 + k + 0], W1[(k0 + k + 0) * D_HID + j], a0);
            a1 = fmaf(h[k0 + k + 1], W1[(k0 + k + 1) * D_HID + j], a1);
            a2 = fmaf(h[k0 + k + 2], W1[(k0 + k + 2) * D_HID + j], a2);
            a3 = fmaf(h[k0 + k + 3], W1[(k0 + k + 3) * D_HID + j], a3);
        }
        const float p = (a0 + a1) + (a2 + a3);
        if (hf == 1) part[j] = p;
        __syncthreads();
        if (hf == 0) {
            const float acc = b1[j] + p + part[j];
            x1[j] = acc / (1.0f + expf(-acc));     // silu
        }
        __syncthreads();
    }

    // ---- layer 2 + dot with W3 ; k-range split 64/64 across hf ----
    {
        const int k0 = hf * 64;
        float a0 = 0.f, a1 = 0.f, a2 = 0.f, a3 = 0.f;
        #pragma unroll
        for (int k = 0; k < 64; k += 4) {
            a0 = fmaf(x1[k0 + k + 0], W2[(k0 + k + 0) * D_HID + j], a0);
            a1 = fmaf(x1[k0 + k + 1], W2[(k0 + k + 1) * D_HID + j], a1);
            a2 = fmaf(x1[k0 + k + 2], W2[(k0 + k + 2) * D_HID + j], a2);
            a3 = fmaf(x1[k0 + k + 3], W2[(k0 + k + 3) * D_HID + j], a3);
        }
        const float p = (a0 + a1) + (a2 + a3);
        if (hf == 1) part[j] = p;
        __syncthreads();

        float r = 0.f;
        if (hf == 0) {
            const float acc2 = b2[j] + p + part[j];
            const float s2 = acc2 / (1.0f + expf(-acc2));
            r = s2 * W3[j];
        }
        // threads 0..127 (hf==0) are waves 0,1: shuffle-reduce each
        #pragma unroll
        for (int off = 32; off > 0; off >>= 1)
            r += __shfl_down(r, off, 64);
        if (hf == 0 && (t & 63) == 0) wsum[t >> 6] = r;
        __syncthreads();
        if (t == 0) Etab[zz] = wsum[0] + wsum[1] + b3[0];
    }
}

// ---------------------------------------------------------------------------
// Kernel 2: flat chunked pass. Block k owns atoms [k*1024, k*1024+1024):
// one int4 of z + one int4 of batch per thread (perfectly coalesced),
// register run-accumulation over the sorted batch ids, flush to 16 LDS bins,
// <=NBINS global atomics per block. Also zeroes the force output.
// ---------------------------------------------------------------------------
__global__ __launch_bounds__(256)
void mace_sum_kernel(const int* __restrict__ z,
                     const int* __restrict__ batch,
                     const float* __restrict__ EtabG,
                     float* __restrict__ energy,
                     float4* __restrict__ forces4,
                     int n, int nblk, int nf4) {
    __shared__ float etab_s[NUM_EL];
    __shared__ float bins[NBINS];
    __shared__ int   base_s;
    const int t   = threadIdx.x;
    const int bid = blockIdx.x;
    const int chunk = bid * CHUNK;

    if (t < NUM_EL) etab_s[t] = EtabG[t];
    if (t < NBINS)  bins[t] = 0.f;
    if (t == 0)     base_s = batch[chunk];

    // zero forces (grid-strided float4; ~3 per thread)
    for (int i = bid * 256 + t; i < nf4; i += nblk * 256)
        forces4[i] = make_float4(0.f, 0.f, 0.f, 0.f);

    __syncthreads();
    const int base = base_s;

    const int i4 = (chunk >> 2) + t;
    if (i4 < (n >> 2)) {
        const int4 zv = ((const int4*)z)[i4];
        const int4 bv = ((const int4*)batch)[i4];
        const float e0 = etab_s[zv.x], e1 = etab_s[zv.y];
        const float e2 = etab_s[zv.z], e3 = etab_s[zv.w];

        // run-accumulate over sorted batch ids (<=2 runs per thread typical)
        float acc = e0;
        int   bc  = bv.x;
        #define FLUSH()                                                     \
            do {                                                            \
                const int bin = bc - base;                                  \
                if (bin < NBINS) atomicAdd(&bins[bin], acc);                \
                else             atomicAdd(&energy[bc], acc);               \
            } while (0)
        if (bv.y == bc) acc += e1; else { FLUSH(); bc = bv.y; acc = e1; }
        if (bv.z == bc) acc += e2; else { FLUSH(); bc = bv.z; acc = e2; }
        if (bv.w == bc) acc += e3; else { FLUSH(); bc = bv.w; acc = e3; }
        FLUSH();
        #undef FLUSH
    }

    // scalar tail if n % 4 != 0 (not hit for n = 1e6; cheap insurance)
    if (bid == nblk - 1 && t == 0) {
        for (int i = (n >> 2) << 2; i < n; ++i)
            atomicAdd(&energy[batch[i]], etab_s[z[i]]);
    }

    __syncthreads();
    if (t < NBINS) {
        const float v = bins[t];
        if (v != 0.f) atomicAdd(&energy[base + t], v);  // in-bounds: v!=0 => base+t was a real id
    }
}

extern "C" void kernel_launch(void* const* d_in, const int* in_sizes, int n_in,
                              void* d_out, int out_size, void* d_ws, size_t ws_size,
                              hipStream_t stream) {
    // 0 positions, 1 embed, 2 W1, 3 b1, 4 W2, 5 b2, 6 W3, 7 b3,
    // 8 atomic_numbers, 9 batch
    const float* embed = (const float*)d_in[1];
    const float* W1    = (const float*)d_in[2];
    const float* b1    = (const float*)d_in[3];
    const float* W2    = (const float*)d_in[4];
    const float* b2    = (const float*)d_in[5];
    const float* W3    = (const float*)d_in[6];
    const float* b3    = (const float*)d_in[7];
    const int*   z     = (const int*)d_in[8];
    const int*   batch = (const int*)d_in[9];
    const int    n     = in_sizes[8];               // 1,000,000

    const int B    = out_size - 3 * n;              // 1024
    const int nf4  = (3 * n) / 4;                   // 750,000
    const int nblk = (n + CHUNK - 1) / CHUNK;       // 977

    float*  energy  = (float*)d_out;                 // [B]
    float4* forces4 = (float4*)((float*)d_out + B);  // [3N], 16B-aligned
    float*  Etab    = (float*)d_ws;                  // 118 floats

    mace_etab_kernel<<<NUM_EL, 256, 0, stream>>>(embed, W1, b1, W2, b2, W3, b3,
                                                 Etab, energy, B);
    mace_sum_kernel<<<nblk, 256, 0, stream>>>(z, batch, Etab, energy, forces4,
                                              n, nblk, nf4);
}